// Round 4
// baseline (511.750 us; speedup 1.0000x reference)
//
#include <hip/hip_runtime.h>
#include <hip/hip_bf16.h>

#define HID 101
#define BATCH 1024
#define RPB 4
#define NBLK 256
#define NTHR 512

#define A1SZ  (7*4*4*512)    // 57344 halfs
#define A2SZ  (7*4*8*512)    // 114688 halfs
#define A2OFF A1SZ
#define AOOFF (A1SZ + A2SZ)  // 172032
#define AOSZ  (4*512)

typedef _Float16 h8 __attribute__((ext_vector_type(8)));
typedef float f4 __attribute__((ext_vector_type(4)));

// ---------------------------------------------------------------------------
// prep: pack A-operand fragments (f16) for mfma_f32_16x16x32_f16.
// Fragment: lane l holds A[row=l&15][k = kt*32 + (l>>4)*8 + i], i=0..7.
// L1 (A1, KT=4, K=128): k<101 -> W_hh1[g][k]; k=101..103 -> W_ih1[g][k-101];
//                       k==104 -> b_ih1[g]+b_hh1[g] (B k=104 slot is const 1).
// L2 (A2, KT=8, K=256): k<101 -> W_ih2[g][k]; k==104 -> b_ih2[g]+b_hh2[g];
//                       k=128..228 -> W_hh2[g][k-128].
// Aout (4 frags): row j<3: k<101 -> Wl[j][k].
// ---------------------------------------------------------------------------
__global__ void prep_kernel(const float* __restrict__ W_ih1, const float* __restrict__ W_hh1,
                            const float* __restrict__ b_ih1, const float* __restrict__ b_hh1,
                            const float* __restrict__ W_ih2, const float* __restrict__ W_hh2,
                            const float* __restrict__ b_ih2, const float* __restrict__ b_hh2,
                            const float* __restrict__ Wl, _Float16* __restrict__ wsA) {
    int idx = blockIdx.x * blockDim.x + threadIdx.x;
    int stride = gridDim.x * blockDim.x;
    for (int t = idx; t < A1SZ; t += stride) {
        int i = t & 7, lane = (t >> 3) & 63, kt = (t >> 9) & 3, tau = (t >> 11) & 3, w = t >> 13;
        int k = kt * 32 + ((lane >> 4) & 3) * 8 + i;
        int u = 16 * w + (lane & 15);
        float v = 0.f;
        if (u < HID) {
            int g = tau * HID + u;
            if (k < HID) v = W_hh1[g * HID + k];
            else if (k >= 101 && k <= 103) v = W_ih1[g * 3 + (k - 101)];
            else if (k == 104) v = b_ih1[g] + b_hh1[g];
        }
        wsA[t] = (_Float16)v;
    }
    for (int t = idx; t < A2SZ; t += stride) {
        int i = t & 7, lane = (t >> 3) & 63, kt = (t >> 9) & 7, tau = (t >> 12) & 3, w = t >> 14;
        int k = kt * 32 + ((lane >> 4) & 3) * 8 + i;
        int u = 16 * w + (lane & 15);
        float v = 0.f;
        if (u < HID) {
            int g = tau * HID + u;
            if (k < HID) v = W_ih2[g * HID + k];
            else if (k == 104) v = b_ih2[g] + b_hh2[g];
            else if (k >= 128 && k < 128 + HID) v = W_hh2[g * HID + (k - 128)];
        }
        wsA[A2OFF + t] = (_Float16)v;
    }
    for (int t = idx; t < AOSZ; t += stride) {
        int i = t & 7, lane = (t >> 3) & 63, kt = (t >> 9) & 3;
        int k = kt * 32 + ((lane >> 4) & 3) * 8 + i;
        int j = lane & 15;
        float v = (j < 3 && k < HID) ? Wl[j * HID + k] : 0.f;
        wsA[AOOFF + t] = (_Float16)v;
    }
}

__device__ __forceinline__ float sigm(float z) {
    return __builtin_amdgcn_rcpf(1.f + __expf(-z));
}
__device__ __forceinline__ float tanhf_(float z) {
    return 1.f - 2.f * __builtin_amdgcn_rcpf(__expf(2.f * z) + 1.f);
}

// ---------------------------------------------------------------------------
// persistent kernel: 256 blocks x 512 thr (8 waves). Waves 0-6: units 16w..16w+15
// for all 4 gates (weights pinned in AGPRs). Wave 7: out-MFMA + x staging.
// LDS B-buffers swizzled: col c of k-quadrant q stored at position (c+4q)&15
// so the 16 active-lane b128 reads cover all 32 banks (2-way, free).
// ---------------------------------------------------------------------------
__global__ __launch_bounds__(NTHR, 2) void lstm_kernel(
    const float* __restrict__ input, const _Float16* __restrict__ wsA,
    const float* __restrict__ bl, int T, int steps, float* __restrict__ out)
{
    const int tid = threadIdx.x;
    const int wid = tid >> 6, lane = tid & 63;
    const int q = lane >> 4, col = lane & 15;
    const int r0 = blockIdx.x * RPB;
    const int ostride = steps * 3;

    __shared__ _Float16 Hb[2][2048];   // h1 (k<101) + x (k101..103) + bias=1 (k104)
    __shared__ _Float16 K2b[2][2048];  // h2 (k<101)
    __shared__ float zw[7][4][4][16];  // per-wave z exchange

    // --- weights pinned into AGPRs (cannot be rematerialized: asm results) ---
    h8 A1r[4][4], A2r[4][8];
    if (wid < 7) {
        #pragma unroll
        for (int tau = 0; tau < 4; tau++) {
            #pragma unroll
            for (int kt = 0; kt < 4; kt++) {
                h8 w = *(const h8*)(wsA + (size_t)(((wid * 4 + tau) * 4 + kt) * 64 + lane) * 8);
                asm volatile("" : "=a"(A1r[tau][kt]) : "0"(w));
                __builtin_amdgcn_sched_barrier(0);
            }
            #pragma unroll
            for (int kt = 0; kt < 8; kt++) {
                h8 w = *(const h8*)(wsA + (size_t)A2OFF + (size_t)(((wid * 4 + tau) * 8 + kt) * 64 + lane) * 8);
                asm volatile("" : "=a"(A2r[tau][kt]) : "0"(w));
                __builtin_amdgcn_sched_barrier(0);
            }
        }
    } else {
        #pragma unroll
        for (int kt = 0; kt < 4; kt++) {
            h8 w = *(const h8*)(wsA + (size_t)AOOFF + (size_t)(kt * 64 + lane) * 8);
            asm volatile("" : "=a"(A2r[0][kt]) : "0"(w));
            __builtin_amdgcn_sched_barrier(0);
        }
    }
    const float bl0 = bl[0], bl1 = bl[1], bl2 = bl[2];

    // loop-invariant lane geometry
    const int r_ew = lane & 3, ul = lane >> 2;
    const int u = 16 * wid + ul;
    const bool ewv = (wid < 7) && (u < HID);
    const int qfu = (u >> 3) & 3;
    const int hslot = (((u >> 5) * 4 + qfu) * 16 + ((r_ew + 4 * qfu) & 15)) * 8 + (u & 7);
    const int boff = (q * 16 + ((col + 4 * q) & 15)) * 8;   // swizzled B-frag offset
    const int xr = lane / 3, xj = lane - 3 * xr;            // wave7 lanes<12
    const int xoff = (12 * 16 + xr) * 8 + 5 + xj;           // x slot (k=101+xj), qf=0: no swz

    // ---- prologue ----
    for (int i2 = tid; i2 < 2048; i2 += NTHR) {
        Hb[0][i2] = (_Float16)0.f; Hb[1][i2] = (_Float16)0.f;
        K2b[0][i2] = (_Float16)0.f; K2b[1][i2] = (_Float16)0.f;
    }
    __syncthreads();
    if (tid < 16) {   // bias slot k=104 (kt=3,qf=1,i=0): position (c+4)&15
        int p = (tid + 4) & 15;
        Hb[0][(13 * 16 + p) * 8] = (_Float16)1.0f;
        Hb[1][(13 * 16 + p) * 8] = (_Float16)1.0f;
    }
    if (tid < 12) {   // x(0) -> Hb[1]  (k=101+j: kt=3,qf=0 -> unswizzled)
        int r = tid / 3, j = tid - 3 * (tid / 3);
        Hb[1][(12 * 16 + r) * 8 + 5 + j] = (_Float16)input[(size_t)(r0 + r) * T * 3 + j];
    }
    float c1 = 0.f, c2 = 0.f;
    __syncthreads();

    auto STEP = [&](int t, _Float16* Hrd, _Float16* Hwr, _Float16* K2rd, _Float16* K2wr, bool fut) {
        float xv = 0.f;
        if (fut) {
            // out(t-1) must be ready before L1(t) reads x slots
            if (wid == 7) {
                f4 ao = {0.f, 0.f, 0.f, 0.f};
                #pragma unroll
                for (int kt = 0; kt < 4; kt++) {
                    h8 b = (_Float16)0.f;
                    if (col < 4) b = *(const h8*)(K2rd + kt * 512 + boff);
                    ao = __builtin_amdgcn_mfma_f32_16x16x32_f16(A2r[0][kt], b, ao, 0, 0, 0);
                }
                if (lane < 4) {
                    float o0 = ao[0] + bl0, o1 = ao[1] + bl1, o2 = ao[2] + bl2;
                    float* op = out + (size_t)(r0 + lane) * ostride + (size_t)(t - 1) * 3;
                    op[0] = o0; op[1] = o1; op[2] = o2;
                    Hrd[(12 * 16 + lane) * 8 + 5] = (_Float16)o0;
                    Hrd[(12 * 16 + lane) * 8 + 6] = (_Float16)o1;
                    Hrd[(12 * 16 + lane) * 8 + 7] = (_Float16)o2;
                }
            }
            __syncthreads();
        }
        // ---- phase A: L1 MFMA + ew1 ; wave7: out(t-1) + x load ----
        if (wid < 7) {
            f4 acc0 = {0.f,0.f,0.f,0.f}, acc1 = acc0, acc2 = acc0, acc3 = acc0;
            #pragma unroll
            for (int kt = 0; kt < 4; kt++) {
                h8 b = (_Float16)0.f;
                if (col < 4) b = *(const h8*)(Hrd + kt * 512 + boff);
                acc0 = __builtin_amdgcn_mfma_f32_16x16x32_f16(A1r[0][kt], b, acc0, 0, 0, 0);
                acc1 = __builtin_amdgcn_mfma_f32_16x16x32_f16(A1r[1][kt], b, acc1, 0, 0, 0);
                acc2 = __builtin_amdgcn_mfma_f32_16x16x32_f16(A1r[2][kt], b, acc2, 0, 0, 0);
                acc3 = __builtin_amdgcn_mfma_f32_16x16x32_f16(A1r[3][kt], b, acc3, 0, 0, 0);
            }
            if (col < 4) {
                *(f4*)&zw[wid][0][col][4 * q] = acc0;
                *(f4*)&zw[wid][1][col][4 * q] = acc1;
                *(f4*)&zw[wid][2][col][4 * q] = acc2;
                *(f4*)&zw[wid][3][col][4 * q] = acc3;
            }
            float z0 = zw[wid][0][r_ew][ul], z1 = zw[wid][1][r_ew][ul];
            float z2 = zw[wid][2][r_ew][ul], z3 = zw[wid][3][r_ew][ul];
            float ig = sigm(z0), fg = sigm(z1), gg = tanhf_(z2), og = sigm(z3);
            c1 = fg * c1 + ig * gg;
            float h1v = og * tanhf_(c1);
            if (ewv) Hwr[hslot] = (_Float16)h1v;
        } else {
            if (!fut) {
                if (t > 0) {
                    f4 ao = {0.f, 0.f, 0.f, 0.f};
                    #pragma unroll
                    for (int kt = 0; kt < 4; kt++) {
                        h8 b = (_Float16)0.f;
                        if (col < 4) b = *(const h8*)(K2rd + kt * 512 + boff);
                        ao = __builtin_amdgcn_mfma_f32_16x16x32_f16(A2r[0][kt], b, ao, 0, 0, 0);
                    }
                    if (lane < 4) {
                        float* op = out + (size_t)(r0 + lane) * ostride + (size_t)(t - 1) * 3;
                        op[0] = ao[0] + bl0; op[1] = ao[1] + bl1; op[2] = ao[2] + bl2;
                    }
                }
                if (t + 1 < T && lane < 12)
                    xv = input[(size_t)(r0 + xr) * T * 3 + (size_t)(t + 1) * 3 + xj];
            }
        }
        __syncthreads();   // h1(t) visible
        // ---- phase B: L2 MFMA + ew2 ; wave7: stage x(t+1) ----
        if (wid < 7) {
            f4 acc0 = {0.f,0.f,0.f,0.f}, acc1 = acc0, acc2 = acc0, acc3 = acc0;
            #pragma unroll
            for (int kt = 0; kt < 4; kt++) {
                h8 b = (_Float16)0.f;
                if (col < 4) b = *(const h8*)(Hwr + kt * 512 + boff);
                acc0 = __builtin_amdgcn_mfma_f32_16x16x32_f16(A2r[0][kt], b, acc0, 0, 0, 0);
                acc1 = __builtin_amdgcn_mfma_f32_16x16x32_f16(A2r[1][kt], b, acc1, 0, 0, 0);
                acc2 = __builtin_amdgcn_mfma_f32_16x16x32_f16(A2r[2][kt], b, acc2, 0, 0, 0);
                acc3 = __builtin_amdgcn_mfma_f32_16x16x32_f16(A2r[3][kt], b, acc3, 0, 0, 0);
            }
            #pragma unroll
            for (int kt = 0; kt < 4; kt++) {
                h8 b = (_Float16)0.f;
                if (col < 4) b = *(const h8*)(K2rd + kt * 512 + boff);
                acc0 = __builtin_amdgcn_mfma_f32_16x16x32_f16(A2r[0][kt + 4], b, acc0, 0, 0, 0);
                acc1 = __builtin_amdgcn_mfma_f32_16x16x32_f16(A2r[1][kt + 4], b, acc1, 0, 0, 0);
                acc2 = __builtin_amdgcn_mfma_f32_16x16x32_f16(A2r[2][kt + 4], b, acc2, 0, 0, 0);
                acc3 = __builtin_amdgcn_mfma_f32_16x16x32_f16(A2r[3][kt + 4], b, acc3, 0, 0, 0);
            }
            if (col < 4) {
                *(f4*)&zw[wid][0][col][4 * q] = acc0;
                *(f4*)&zw[wid][1][col][4 * q] = acc1;
                *(f4*)&zw[wid][2][col][4 * q] = acc2;
                *(f4*)&zw[wid][3][col][4 * q] = acc3;
            }
            float z0 = zw[wid][0][r_ew][ul], z1 = zw[wid][1][r_ew][ul];
            float z2 = zw[wid][2][r_ew][ul], z3 = zw[wid][3][r_ew][ul];
            float ig = sigm(z0), fg = sigm(z1), gg = tanhf_(z2), og = sigm(z3);
            c2 = fg * c2 + ig * gg;
            float h2v = og * tanhf_(c2);
            if (ewv) K2wr[hslot] = (_Float16)h2v;
        } else {
            if (!fut && t + 1 < T && lane < 12)
                Hwr[xoff] = (_Float16)xv;
        }
        __syncthreads();   // h2(t) + x(t+1) visible
    };

    for (int t = 0; t < T; t += 2) {
        STEP(t,     Hb[1], Hb[0], K2b[1], K2b[0], false);
        STEP(t + 1, Hb[0], Hb[1], K2b[0], K2b[1], false);
    }
    for (int t = T; t < steps; t += 2) {
        STEP(t,     Hb[1], Hb[0], K2b[1], K2b[0], true);
        STEP(t + 1, Hb[0], Hb[1], K2b[0], K2b[1], true);
    }
    // epilogue: out(steps-1) from h2(steps-1) in K2b[1]
    if (wid == 7) {
        f4 ao = {0.f, 0.f, 0.f, 0.f};
        #pragma unroll
        for (int kt = 0; kt < 4; kt++) {
            h8 b = (_Float16)0.f;
            if (col < 4) b = *(const h8*)(&K2b[1][0] + kt * 512 + boff);
            ao = __builtin_amdgcn_mfma_f32_16x16x32_f16(A2r[0][kt], b, ao, 0, 0, 0);
        }
        if (lane < 4) {
            float* op = out + (size_t)(r0 + lane) * ostride + (size_t)(steps - 1) * 3;
            op[0] = ao[0] + bl0; op[1] = ao[1] + bl1; op[2] = ao[2] + bl2;
        }
    }
}

extern "C" void kernel_launch(void* const* d_in, const int* in_sizes, int n_in,
                              void* d_out, int out_size, void* d_ws, size_t ws_size,
                              hipStream_t stream) {
    const float* input = (const float*)d_in[0];
    const float* W_ih1 = (const float*)d_in[1];
    const float* W_hh1 = (const float*)d_in[2];
    const float* b_ih1 = (const float*)d_in[3];
    const float* b_hh1 = (const float*)d_in[4];
    const float* W_ih2 = (const float*)d_in[5];
    const float* W_hh2 = (const float*)d_in[6];
    const float* b_ih2 = (const float*)d_in[7];
    const float* b_hh2 = (const float*)d_in[8];
    const float* Wl    = (const float*)d_in[9];
    const float* bl    = (const float*)d_in[10];
    int T = in_sizes[0] / (BATCH * 3);        // 256
    int steps = out_size / (BATCH * 3);       // 288
    _Float16* wsA = (_Float16*)d_ws;

    hipLaunchKernelGGL(prep_kernel, dim3(512), dim3(256), 0, stream,
                       W_ih1, W_hh1, b_ih1, b_hh1, W_ih2, W_hh2, b_ih2, b_hh2, Wl, wsA);
    hipLaunchKernelGGL(lstm_kernel, dim3(NBLK), dim3(NTHR), 0, stream,
                       input, wsA, bl, T, steps, (float*)d_out);
}

// Round 7
// 488.922 us; speedup vs baseline: 1.0467x; 1.0467x over previous
//
#include <hip/hip_runtime.h>
#include <hip/hip_bf16.h>

#define HID 101
#define BATCH 1024
#define RPB 4
#define NBLK 256
#define NTHR 512

#define A1SZ  (7*4*4*512)    // 57344 halfs
#define A2SZ  (7*4*8*512)    // 114688 halfs
#define A2OFF A1SZ
#define AOOFF (A1SZ + A2SZ)  // 172032
#define AOSZ  (4*512)

typedef _Float16 h8 __attribute__((ext_vector_type(8)));
typedef float f4 __attribute__((ext_vector_type(4)));

// ---------------------------------------------------------------------------
// prep: pack A-operand fragments (f16) for mfma_f32_16x16x32_f16.
// Fragment: lane l holds A[row=l&15][k = kt*32 + (l>>4)*8 + i], i=0..7.
// L1 (A1, KT=4, K=128): k<101->W_hh1[g][k]; k=101..103->W_ih1; k==104->b1
//   (B k=104 slot is const 1).
// L2 (A2, KT=8, K=256): k<101->W_ih2[g][k]; k==104->b2; k=128..228->W_hh2.
// AO (4 frags vs h2 buffer k0..127): row j<3: k<101 -> Wl[j][k].
// ---------------------------------------------------------------------------
__global__ void prep_kernel(const float* __restrict__ W_ih1, const float* __restrict__ W_hh1,
                            const float* __restrict__ b_ih1, const float* __restrict__ b_hh1,
                            const float* __restrict__ W_ih2, const float* __restrict__ W_hh2,
                            const float* __restrict__ b_ih2, const float* __restrict__ b_hh2,
                            const float* __restrict__ Wl, _Float16* __restrict__ wsA) {
    int idx = blockIdx.x * blockDim.x + threadIdx.x;
    int stride = gridDim.x * blockDim.x;
    for (int t = idx; t < A1SZ; t += stride) {
        int i = t & 7, lane = (t >> 3) & 63, kt = (t >> 9) & 3, tau = (t >> 11) & 3, w = t >> 13;
        int k = kt * 32 + ((lane >> 4) & 3) * 8 + i;
        int u = 16 * w + (lane & 15);
        float v = 0.f;
        if (u < HID) {
            int g = tau * HID + u;
            if (k < HID) v = W_hh1[g * HID + k];
            else if (k >= 101 && k <= 103) v = W_ih1[g * 3 + (k - 101)];
            else if (k == 104) v = b_ih1[g] + b_hh1[g];
        }
        wsA[t] = (_Float16)v;
    }
    for (int t = idx; t < A2SZ; t += stride) {
        int i = t & 7, lane = (t >> 3) & 63, kt = (t >> 9) & 7, tau = (t >> 12) & 3, w = t >> 14;
        int k = kt * 32 + ((lane >> 4) & 3) * 8 + i;
        int u = 16 * w + (lane & 15);
        float v = 0.f;
        if (u < HID) {
            int g = tau * HID + u;
            if (k < HID) v = W_ih2[g * HID + k];
            else if (k == 104) v = b_ih2[g] + b_hh2[g];
            else if (k >= 128 && k < 128 + HID) v = W_hh2[g * HID + (k - 128)];
        }
        wsA[A2OFF + t] = (_Float16)v;
    }
    for (int t = idx; t < AOSZ; t += stride) {
        int i = t & 7, lane = (t >> 3) & 63, kt = (t >> 9) & 3;
        int k = kt * 32 + ((lane >> 4) & 3) * 8 + i;
        int j = lane & 15;
        float v = (j < 3 && k < HID) ? Wl[j * HID + k] : 0.f;
        wsA[AOOFF + t] = (_Float16)v;
    }
}

__device__ __forceinline__ float sigm(float z) {
    return __builtin_amdgcn_rcpf(1.f + __expf(-z));
}
__device__ __forceinline__ float tanhf_(float z) {
    return 1.f - 2.f * __builtin_amdgcn_rcpf(__expf(2.f * z) + 1.f);
}

// ---------------------------------------------------------------------------
// persistent kernel: 256 blocks x 512 thr (8 waves). Waves 0-6: units 16w..16w+15
// for all 4 gates. Wave 7: out-MFMA + x staging.
// Weights are loaded VOLATILE: a volatile load must execute exactly once, so the
// compiler cannot rematerialize it inside the time loop -> fragments stay
// register-resident for all 288 steps.
// ---------------------------------------------------------------------------
__global__ __launch_bounds__(NTHR, 2) void lstm_kernel(
    const float* __restrict__ input, const _Float16* __restrict__ wsA,
    const float* __restrict__ bl, int T, int steps, float* __restrict__ out)
{
    const int tid = threadIdx.x;
    const int wid = tid >> 6, lane = tid & 63;
    const int q = lane >> 4, col = lane & 15;
    const int r0 = blockIdx.x * RPB;
    const int ostride = steps * 3;

    __shared__ _Float16 Hb[2][2048];   // h1 (k<101) + x (k101..103) + bias=1 (k104)
    __shared__ _Float16 K2b[2][2048];  // h2 (k<101)
    __shared__ float zw[7][4][4][16];  // per-wave z exchange

    // --- weights: volatile loads -> cannot be rematerialized, stay in regs ---
    h8 A1[4][4];
    h8 A2[4][8];
    if (wid < 7) {
        #pragma unroll
        for (int tau = 0; tau < 4; tau++) {
            #pragma unroll
            for (int kt = 0; kt < 4; kt++)
                A1[tau][kt] = *(const volatile h8*)(
                    wsA + ((size_t)((wid * 4 + tau) * 4 + kt) * 512 + lane * 8));
            #pragma unroll
            for (int kt = 0; kt < 8; kt++)
                A2[tau][kt] = *(const volatile h8*)(
                    wsA + (size_t)A2OFF + ((size_t)((wid * 4 + tau) * 8 + kt) * 512 + lane * 8));
        }
    } else {
        #pragma unroll
        for (int kt = 0; kt < 4; kt++)
            A2[0][kt] = *(const volatile h8*)(
                wsA + (size_t)AOOFF + ((size_t)(kt) * 512 + lane * 8));
    }
    const float bl0 = bl[0], bl1 = bl[1], bl2 = bl[2];

    // loop-invariant lane geometry
    const int r_ew = lane & 3, ul = lane >> 2;
    const int u = 16 * wid + ul;
    const bool ewv = (wid < 7) && (u < HID);
    const int qfu = (u >> 3) & 3;
    const int hslot = (((u >> 5) * 4 + qfu) * 16 + r_ew) * 8 + (u & 7);
    const int boff = (q * 16 + col) * 8;
    const int xr = lane / 3, xj = lane - 3 * xr;            // wave7 lanes<12
    const int xoff = (12 * 16 + xr) * 8 + 5 + xj;           // x slot (k=101+xj)

    // ---- prologue ----
    for (int i2 = tid; i2 < 2048; i2 += NTHR) {
        Hb[0][i2] = (_Float16)0.f; Hb[1][i2] = (_Float16)0.f;
        K2b[0][i2] = (_Float16)0.f; K2b[1][i2] = (_Float16)0.f;
    }
    __syncthreads();
    if (tid < 16) {   // bias slot k=104 (kt=3,qf=1,i=0)
        Hb[0][(13 * 16 + tid) * 8] = (_Float16)1.0f;
        Hb[1][(13 * 16 + tid) * 8] = (_Float16)1.0f;
    }
    if (tid < 12) {   // x(0) -> Hb[1]
        int r = tid / 3, j = tid - 3 * (tid / 3);
        Hb[1][(12 * 16 + r) * 8 + 5 + j] = (_Float16)input[(size_t)(r0 + r) * T * 3 + j];
    }
    float c1 = 0.f, c2 = 0.f;
    __syncthreads();

    auto STEP = [&](int t, _Float16* Hrd, _Float16* Hwr, _Float16* K2rd, _Float16* K2wr, bool fut) {
        float xv = 0.f;
        if (fut) {
            // out(t-1) must be ready before L1(t) reads x slots
            if (wid == 7) {
                f4 ao = {0.f, 0.f, 0.f, 0.f};
                #pragma unroll
                for (int kt = 0; kt < 4; kt++) {
                    h8 b = *(const h8*)(K2rd + kt * 512 + boff);
                    ao = __builtin_amdgcn_mfma_f32_16x16x32_f16(A2[0][kt], b, ao, 0, 0, 0);
                }
                if (lane < 4) {
                    float o0 = ao[0] + bl0, o1 = ao[1] + bl1, o2 = ao[2] + bl2;
                    float* op = out + (size_t)(r0 + lane) * ostride + (size_t)(t - 1) * 3;
                    op[0] = o0; op[1] = o1; op[2] = o2;
                    Hrd[(12 * 16 + lane) * 8 + 5] = (_Float16)o0;
                    Hrd[(12 * 16 + lane) * 8 + 6] = (_Float16)o1;
                    Hrd[(12 * 16 + lane) * 8 + 7] = (_Float16)o2;
                }
            }
            __syncthreads();
        }
        // ---- phase A: L1 MFMA + ew1 ; wave7: out(t-1) + x load ----
        if (wid < 7) {
            f4 acc0 = {0.f,0.f,0.f,0.f}, acc1 = acc0, acc2 = acc0, acc3 = acc0;
            #pragma unroll
            for (int kt = 0; kt < 4; kt++) {
                h8 b = *(const h8*)(Hrd + kt * 512 + boff);
                acc0 = __builtin_amdgcn_mfma_f32_16x16x32_f16(A1[0][kt], b, acc0, 0, 0, 0);
                acc1 = __builtin_amdgcn_mfma_f32_16x16x32_f16(A1[1][kt], b, acc1, 0, 0, 0);
                acc2 = __builtin_amdgcn_mfma_f32_16x16x32_f16(A1[2][kt], b, acc2, 0, 0, 0);
                acc3 = __builtin_amdgcn_mfma_f32_16x16x32_f16(A1[3][kt], b, acc3, 0, 0, 0);
            }
            if (col < 4) {
                *(f4*)&zw[wid][0][col][4 * q] = acc0;
                *(f4*)&zw[wid][1][col][4 * q] = acc1;
                *(f4*)&zw[wid][2][col][4 * q] = acc2;
                *(f4*)&zw[wid][3][col][4 * q] = acc3;
            }
            float z0 = zw[wid][0][r_ew][ul], z1 = zw[wid][1][r_ew][ul];
            float z2 = zw[wid][2][r_ew][ul], z3 = zw[wid][3][r_ew][ul];
            float ig = sigm(z0), fg = sigm(z1), gg = tanhf_(z2), og = sigm(z3);
            c1 = fg * c1 + ig * gg;
            float h1v = og * tanhf_(c1);
            if (ewv) Hwr[hslot] = (_Float16)h1v;
        } else {
            if (!fut) {
                if (t > 0) {
                    f4 ao = {0.f, 0.f, 0.f, 0.f};
                    #pragma unroll
                    for (int kt = 0; kt < 4; kt++) {
                        h8 b = *(const h8*)(K2rd + kt * 512 + boff);
                        ao = __builtin_amdgcn_mfma_f32_16x16x32_f16(A2[0][kt], b, ao, 0, 0, 0);
                    }
                    if (lane < 4) {
                        float* op = out + (size_t)(r0 + lane) * ostride + (size_t)(t - 1) * 3;
                        op[0] = ao[0] + bl0; op[1] = ao[1] + bl1; op[2] = ao[2] + bl2;
                    }
                }
                if (t + 1 < T && lane < 12)
                    xv = input[(size_t)(r0 + xr) * T * 3 + (size_t)(t + 1) * 3 + xj];
            }
        }
        __syncthreads();   // h1(t) visible
        // ---- phase B: L2 MFMA + ew2 ; wave7: stage x(t+1) ----
        if (wid < 7) {
            f4 acc0 = {0.f,0.f,0.f,0.f}, acc1 = acc0, acc2 = acc0, acc3 = acc0;
            #pragma unroll
            for (int kt = 0; kt < 4; kt++) {
                h8 b = *(const h8*)(Hwr + kt * 512 + boff);
                acc0 = __builtin_amdgcn_mfma_f32_16x16x32_f16(A2[0][kt], b, acc0, 0, 0, 0);
                acc1 = __builtin_amdgcn_mfma_f32_16x16x32_f16(A2[1][kt], b, acc1, 0, 0, 0);
                acc2 = __builtin_amdgcn_mfma_f32_16x16x32_f16(A2[2][kt], b, acc2, 0, 0, 0);
                acc3 = __builtin_amdgcn_mfma_f32_16x16x32_f16(A2[3][kt], b, acc3, 0, 0, 0);
            }
            #pragma unroll
            for (int kt = 0; kt < 4; kt++) {
                h8 b = *(const h8*)(K2rd + kt * 512 + boff);
                acc0 = __builtin_amdgcn_mfma_f32_16x16x32_f16(A2[0][kt + 4], b, acc0, 0, 0, 0);
                acc1 = __builtin_amdgcn_mfma_f32_16x16x32_f16(A2[1][kt + 4], b, acc1, 0, 0, 0);
                acc2 = __builtin_amdgcn_mfma_f32_16x16x32_f16(A2[2][kt + 4], b, acc2, 0, 0, 0);
                acc3 = __builtin_amdgcn_mfma_f32_16x16x32_f16(A2[3][kt + 4], b, acc3, 0, 0, 0);
            }
            if (col < 4) {
                *(f4*)&zw[wid][0][col][4 * q] = acc0;
                *(f4*)&zw[wid][1][col][4 * q] = acc1;
                *(f4*)&zw[wid][2][col][4 * q] = acc2;
                *(f4*)&zw[wid][3][col][4 * q] = acc3;
            }
            float z0 = zw[wid][0][r_ew][ul], z1 = zw[wid][1][r_ew][ul];
            float z2 = zw[wid][2][r_ew][ul], z3 = zw[wid][3][r_ew][ul];
            float ig = sigm(z0), fg = sigm(z1), gg = tanhf_(z2), og = sigm(z3);
            c2 = fg * c2 + ig * gg;
            float h2v = og * tanhf_(c2);
            if (ewv) K2wr[hslot] = (_Float16)h2v;
        } else {
            if (!fut && t + 1 < T && lane < 12)
                Hwr[xoff] = (_Float16)xv;
        }
        __syncthreads();   // h2(t) + x(t+1) visible
    };

    for (int t = 0; t < T; t += 2) {
        STEP(t,     Hb[1], Hb[0], K2b[1], K2b[0], false);
        STEP(t + 1, Hb[0], Hb[1], K2b[0], K2b[1], false);
    }
    for (int t = T; t < steps; t += 2) {
        STEP(t,     Hb[1], Hb[0], K2b[1], K2b[0], true);
        STEP(t + 1, Hb[0], Hb[1], K2b[0], K2b[1], true);
    }
    // epilogue: out(steps-1) from h2(steps-1) in K2b[1]
    if (wid == 7) {
        f4 ao = {0.f, 0.f, 0.f, 0.f};
        #pragma unroll
        for (int kt = 0; kt < 4; kt++) {
            h8 b = *(const h8*)(&K2b[1][0] + kt * 512 + boff);
            ao = __builtin_amdgcn_mfma_f32_16x16x32_f16(A2[0][kt], b, ao, 0, 0, 0);
        }
        if (lane < 4) {
            float* op = out + (size_t)(r0 + lane) * ostride + (size_t)(steps - 1) * 3;
            op[0] = ao[0] + bl0; op[1] = ao[1] + bl1; op[2] = ao[2] + bl2;
        }
    }
}

extern "C" void kernel_launch(void* const* d_in, const int* in_sizes, int n_in,
                              void* d_out, int out_size, void* d_ws, size_t ws_size,
                              hipStream_t stream) {
    const float* input = (const float*)d_in[0];
    const float* W_ih1 = (const float*)d_in[1];
    const float* W_hh1 = (const float*)d_in[2];
    const float* b_ih1 = (const float*)d_in[3];
    const float* b_hh1 = (const float*)d_in[4];
    const float* W_ih2 = (const float*)d_in[5];
    const float* W_hh2 = (const float*)d_in[6];
    const float* b_ih2 = (const float*)d_in[7];
    const float* b_hh2 = (const float*)d_in[8];
    const float* Wl    = (const float*)d_in[9];
    const float* bl    = (const float*)d_in[10];
    int T = in_sizes[0] / (BATCH * 3);        // 256
    int steps = out_size / (BATCH * 3);       // 288
    _Float16* wsA = (_Float16*)d_ws;

    hipLaunchKernelGGL(prep_kernel, dim3(512), dim3(256), 0, stream,
                       W_ih1, W_hh1, b_ih1, b_hh1, W_ih2, W_hh2, b_ih2, b_hh2, Wl, wsA);
    hipLaunchKernelGGL(lstm_kernel, dim3(NBLK), dim3(NTHR), 0, stream,
                       input, wsA, bl, T, steps, (float*)d_out);
}

// Round 8
// 472.894 us; speedup vs baseline: 1.0822x; 1.0339x over previous
//
#include <hip/hip_runtime.h>
#include <hip/hip_bf16.h>

#define HID 101
#define BATCH 1024
#define RPB 4
#define NBLK 256
#define NTHR 512

#define A1SZ  (7*4*4*512)    // 57344 halfs
#define A2SZ  (7*4*7*512)    // 100352 halfs
#define A2OFF A1SZ
#define AOOFF (A1SZ + A2SZ)  // 157696
#define AOSZ  (4*512)

typedef _Float16 h8 __attribute__((ext_vector_type(8)));
typedef float f4 __attribute__((ext_vector_type(4)));

// ---------------------------------------------------------------------------
// Combined state vector (K=224, 7 k-tiles of 32):
//   k 0..100 : h1    k 101..103 : x    k 104 : one    k 112..212 : h2
// A1 (L1, kt0..3): k<101->W_hh1[g][k]; 101..103->W_ih1; 104->b1; else 0.
// A2 (L2, kt0..6): k<101->W_ih2[g][k]; 104->b2; 112..212->W_hh2[g][k-112]; else 0.
// AO (out head, frags for kt3..6): row j<3: k 112..212 -> Wl[j][k-112]; else 0.
// Fragment: lane l holds A[row=l&15][k = kt*32 + ((l>>4)&3)*8 + i], i=0..7.
// ---------------------------------------------------------------------------
__global__ void prep_kernel(const float* __restrict__ W_ih1, const float* __restrict__ W_hh1,
                            const float* __restrict__ b_ih1, const float* __restrict__ b_hh1,
                            const float* __restrict__ W_ih2, const float* __restrict__ W_hh2,
                            const float* __restrict__ b_ih2, const float* __restrict__ b_hh2,
                            const float* __restrict__ Wl, _Float16* __restrict__ wsA) {
    int idx = blockIdx.x * blockDim.x + threadIdx.x;
    int stride = gridDim.x * blockDim.x;
    for (int t = idx; t < A1SZ; t += stride) {
        int i = t & 7, lane = (t >> 3) & 63, kt = (t >> 9) & 3, tau = (t >> 11) & 3, w = t >> 13;
        int k = kt * 32 + ((lane >> 4) & 3) * 8 + i;
        int u = 16 * w + (lane & 15);
        float v = 0.f;
        if (u < HID) {
            int g = tau * HID + u;
            if (k < HID) v = W_hh1[g * HID + k];
            else if (k >= 101 && k <= 103) v = W_ih1[g * 3 + (k - 101)];
            else if (k == 104) v = b_ih1[g] + b_hh1[g];
        }
        wsA[t] = (_Float16)v;
    }
    for (int t = idx; t < A2SZ; t += stride) {
        int i = t & 7, lane = (t >> 3) & 63;
        int rem = t >> 9;
        int kt = rem % 7; rem /= 7;
        int tau = rem & 3, w = rem >> 2;
        int k = kt * 32 + ((lane >> 4) & 3) * 8 + i;
        int u = 16 * w + (lane & 15);
        float v = 0.f;
        if (u < HID) {
            int g = tau * HID + u;
            if (k < HID) v = W_ih2[g * HID + k];
            else if (k == 104) v = b_ih2[g] + b_hh2[g];
            else if (k >= 112 && k < 213) v = W_hh2[g * HID + (k - 112)];
        }
        wsA[A2OFF + t] = (_Float16)v;
    }
    for (int t = idx; t < AOSZ; t += stride) {
        int i = t & 7, lane = (t >> 3) & 63, kk = (t >> 9) & 3;
        int k = (kk + 3) * 32 + ((lane >> 4) & 3) * 8 + i;
        int j = lane & 15;
        float v = (j < 3 && k >= 112 && k < 213) ? Wl[j * HID + (k - 112)] : 0.f;
        wsA[AOOFF + t] = (_Float16)v;
    }
}

__device__ __forceinline__ float sigm(float z) {
    return __builtin_amdgcn_rcpf(1.f + __expf(-z));
}
__device__ __forceinline__ float tanhf_(float z) {
    return 1.f - 2.f * __builtin_amdgcn_rcpf(__expf(2.f * z) + 1.f);
}

// ---------------------------------------------------------------------------
// persistent kernel: 256 blocks x 512 thr (8 waves). Waves 0-6: units 16w..16w+15
// for all 4 gates (A1 4kt + A2 7kt = 176 weight regs -> total fits 256/wave).
// Wave 7: out-MFMA (Wl vs h2 region) + x staging/feedback.
// Invariant per step t (R=read buf, W=write buf, alternating):
//   phase A: read R kt0..3 -> h1(t) -> W(k0..100)        [W h2-region holds h2(t-1)]
//   phase B: read W kt0..6 -> h2(t) -> R(k112..212)
// All cross-region overlaps multiply zero A-columns (benign).
// ---------------------------------------------------------------------------
__global__ __launch_bounds__(NTHR, 2) void lstm_kernel(
    const float* __restrict__ input, const _Float16* __restrict__ wsA,
    const float* __restrict__ bl, int T, int steps, float* __restrict__ out)
{
    const int tid = threadIdx.x;
    const int wid = tid >> 6, lane = tid & 63;
    const int q = lane >> 4, col = lane & 15;
    const int r0 = blockIdx.x * RPB;
    const int ostride = steps * 3;

    __shared__ _Float16 Sb[2][3584];   // combined state buffers (7 KiB each)
    __shared__ float zw[7][4][4][16];  // per-wave z exchange

    // --- weights: volatile loads -> execute once, stay register-resident ---
    h8 A1[4][4];
    h8 A2[4][7];
    if (wid < 7) {
        #pragma unroll
        for (int tau = 0; tau < 4; tau++) {
            #pragma unroll
            for (int kt = 0; kt < 4; kt++)
                A1[tau][kt] = *(const volatile h8*)(
                    wsA + ((size_t)((wid * 4 + tau) * 4 + kt) * 512 + lane * 8));
            #pragma unroll
            for (int kt = 0; kt < 7; kt++)
                A2[tau][kt] = *(const volatile h8*)(
                    wsA + (size_t)A2OFF + ((size_t)((wid * 4 + tau) * 7 + kt) * 512 + lane * 8));
        }
    } else {
        #pragma unroll
        for (int kt = 0; kt < 4; kt++)
            A2[0][kt] = *(const volatile h8*)(
                wsA + (size_t)AOOFF + ((size_t)(kt) * 512 + lane * 8));
    }
    const float bl0 = bl[0], bl1 = bl[1], bl2 = bl[2];

    // loop-invariant lane geometry
    const int r_ew = lane & 3, ul = lane >> 2;
    const int u = 16 * wid + ul;
    const bool ewv = (wid < 7) && (u < HID);
    const int hs1 = (u >> 3) * 128 + r_ew * 8 + (u & 7);            // h1 slot (k=u)
    const int hs2 = (14 + (u >> 3)) * 128 + r_ew * 8 + (u & 7);     // h2 slot (k=112+u)
    const int boff = (q * 16 + col) * 8;
    const int xr = lane / 3, xj = lane - 3 * xr;                    // wave7 lanes<12
    const int xoff = 12 * 128 + xr * 8 + 5 + xj;                    // x slot (k=101+xj)

    // ---- prologue ----
    for (int i2 = tid; i2 < 3584; i2 += NTHR) {
        Sb[0][i2] = (_Float16)0.f; Sb[1][i2] = (_Float16)0.f;
    }
    __syncthreads();
    if (tid < 16) {   // bias-one slot k=104, both buffers
        Sb[0][13 * 128 + tid * 8] = (_Float16)1.0f;
        Sb[1][13 * 128 + tid * 8] = (_Float16)1.0f;
    }
    if (tid < 12) {   // x(0) -> Sb1 (R at t=0)
        int r = tid / 3, j = tid - 3 * (tid / 3);
        Sb[1][12 * 128 + r * 8 + 5 + j] = (_Float16)input[(size_t)(r0 + r) * T * 3 + j];
    }
    float c1 = 0.f, c2 = 0.f;
    __syncthreads();

    auto STEP = [&](int t, _Float16* R, _Float16* W, bool fut) {
        float xv = 0.f;
        if (fut) {
            // pre-phase: out(t-1) from W h2-region; feedback x(t) -> R x-slots
            if (wid == 7) {
                f4 ao = {0.f, 0.f, 0.f, 0.f};
                #pragma unroll
                for (int kk = 0; kk < 4; kk++) {
                    h8 b = *(const h8*)(W + (kk + 3) * 512 + boff);
                    ao = __builtin_amdgcn_mfma_f32_16x16x32_f16(A2[0][kk], b, ao, 0, 0, 0);
                }
                if (lane < 4) {
                    float o0 = ao[0] + bl0, o1 = ao[1] + bl1, o2 = ao[2] + bl2;
                    float* op = out + (size_t)(r0 + lane) * ostride + (size_t)(t - 1) * 3;
                    op[0] = o0; op[1] = o1; op[2] = o2;
                    R[12 * 128 + lane * 8 + 5] = (_Float16)o0;
                    R[12 * 128 + lane * 8 + 6] = (_Float16)o1;
                    R[12 * 128 + lane * 8 + 7] = (_Float16)o2;
                }
            }
            __syncthreads();
        }
        // ---- phase A: L1 MFMA (R kt0..3) + ew1 -> h1 into W ----
        if (wid < 7) {
            f4 acc0 = {0.f,0.f,0.f,0.f}, acc1 = acc0, acc2 = acc0, acc3 = acc0;
            #pragma unroll
            for (int kt = 0; kt < 4; kt++) {
                h8 b = *(const h8*)(R + kt * 512 + boff);
                acc0 = __builtin_amdgcn_mfma_f32_16x16x32_f16(A1[0][kt], b, acc0, 0, 0, 0);
                acc1 = __builtin_amdgcn_mfma_f32_16x16x32_f16(A1[1][kt], b, acc1, 0, 0, 0);
                acc2 = __builtin_amdgcn_mfma_f32_16x16x32_f16(A1[2][kt], b, acc2, 0, 0, 0);
                acc3 = __builtin_amdgcn_mfma_f32_16x16x32_f16(A1[3][kt], b, acc3, 0, 0, 0);
            }
            if (col < 4) {
                *(f4*)&zw[wid][0][col][4 * q] = acc0;
                *(f4*)&zw[wid][1][col][4 * q] = acc1;
                *(f4*)&zw[wid][2][col][4 * q] = acc2;
                *(f4*)&zw[wid][3][col][4 * q] = acc3;
            }
            float z0 = zw[wid][0][r_ew][ul], z1 = zw[wid][1][r_ew][ul];
            float z2 = zw[wid][2][r_ew][ul], z3 = zw[wid][3][r_ew][ul];
            float ig = sigm(z0), fg = sigm(z1), gg = tanhf_(z2), og = sigm(z3);
            c1 = fg * c1 + ig * gg;
            float h1v = og * tanhf_(c1);
            if (ewv) W[hs1] = (_Float16)h1v;
        } else {
            if (!fut) {
                if (t > 0) {   // out(t-1) from W h2-region (= h2(t-1))
                    f4 ao = {0.f, 0.f, 0.f, 0.f};
                    #pragma unroll
                    for (int kk = 0; kk < 4; kk++) {
                        h8 b = *(const h8*)(W + (kk + 3) * 512 + boff);
                        ao = __builtin_amdgcn_mfma_f32_16x16x32_f16(A2[0][kk], b, ao, 0, 0, 0);
                    }
                    if (lane < 4) {
                        float* op = out + (size_t)(r0 + lane) * ostride + (size_t)(t - 1) * 3;
                        op[0] = ao[0] + bl0; op[1] = ao[1] + bl1; op[2] = ao[2] + bl2;
                    }
                }
                if (t + 1 < T && lane < 12)
                    xv = input[(size_t)(r0 + xr) * T * 3 + (size_t)(t + 1) * 3 + xj];
            }
        }
        __syncthreads();   // h1(t) visible in W
        // ---- phase B: L2 MFMA (W kt0..6) + ew2 -> h2 into R ----
        if (wid < 7) {
            f4 acc0 = {0.f,0.f,0.f,0.f}, acc1 = acc0, acc2 = acc0, acc3 = acc0;
            #pragma unroll
            for (int kt = 0; kt < 7; kt++) {
                h8 b = *(const h8*)(W + kt * 512 + boff);
                acc0 = __builtin_amdgcn_mfma_f32_16x16x32_f16(A2[0][kt], b, acc0, 0, 0, 0);
                acc1 = __builtin_amdgcn_mfma_f32_16x16x32_f16(A2[1][kt], b, acc1, 0, 0, 0);
                acc2 = __builtin_amdgcn_mfma_f32_16x16x32_f16(A2[2][kt], b, acc2, 0, 0, 0);
                acc3 = __builtin_amdgcn_mfma_f32_16x16x32_f16(A2[3][kt], b, acc3, 0, 0, 0);
            }
            if (col < 4) {
                *(f4*)&zw[wid][0][col][4 * q] = acc0;
                *(f4*)&zw[wid][1][col][4 * q] = acc1;
                *(f4*)&zw[wid][2][col][4 * q] = acc2;
                *(f4*)&zw[wid][3][col][4 * q] = acc3;
            }
            float z0 = zw[wid][0][r_ew][ul], z1 = zw[wid][1][r_ew][ul];
            float z2 = zw[wid][2][r_ew][ul], z3 = zw[wid][3][r_ew][ul];
            float ig = sigm(z0), fg = sigm(z1), gg = tanhf_(z2), og = sigm(z3);
            c2 = fg * c2 + ig * gg;
            float h2v = og * tanhf_(c2);
            if (ewv) R[hs2] = (_Float16)h2v;
        } else {
            if (!fut && t + 1 < T && lane < 12)
                W[xoff] = (_Float16)xv;   // x(t+1) -> W (= R of step t+1)
        }
        __syncthreads();   // h2(t) + x(t+1) visible
    };

    for (int t = 0; t < T; t += 2) {
        STEP(t,     Sb[1], Sb[0], false);
        STEP(t + 1, Sb[0], Sb[1], false);
    }
    for (int t = T; t < steps; t += 2) {
        STEP(t,     Sb[1], Sb[0], true);
        STEP(t + 1, Sb[0], Sb[1], true);
    }
    // epilogue: out(steps-1) from h2(steps-1) in Sb0 (steps-1 odd -> h2 -> R=Sb0)
    if (wid == 7) {
        f4 ao = {0.f, 0.f, 0.f, 0.f};
        #pragma unroll
        for (int kk = 0; kk < 4; kk++) {
            h8 b = *(const h8*)(&Sb[0][0] + (kk + 3) * 512 + boff);
            ao = __builtin_amdgcn_mfma_f32_16x16x32_f16(A2[0][kk], b, ao, 0, 0, 0);
        }
        if (lane < 4) {
            float* op = out + (size_t)(r0 + lane) * ostride + (size_t)(steps - 1) * 3;
            op[0] = ao[0] + bl0; op[1] = ao[1] + bl1; op[2] = ao[2] + bl2;
        }
    }
}

extern "C" void kernel_launch(void* const* d_in, const int* in_sizes, int n_in,
                              void* d_out, int out_size, void* d_ws, size_t ws_size,
                              hipStream_t stream) {
    const float* input = (const float*)d_in[0];
    const float* W_ih1 = (const float*)d_in[1];
    const float* W_hh1 = (const float*)d_in[2];
    const float* b_ih1 = (const float*)d_in[3];
    const float* b_hh1 = (const float*)d_in[4];
    const float* W_ih2 = (const float*)d_in[5];
    const float* W_hh2 = (const float*)d_in[6];
    const float* b_ih2 = (const float*)d_in[7];
    const float* b_hh2 = (const float*)d_in[8];
    const float* Wl    = (const float*)d_in[9];
    const float* bl    = (const float*)d_in[10];
    int T = in_sizes[0] / (BATCH * 3);        // 256
    int steps = out_size / (BATCH * 3);       // 288
    _Float16* wsA = (_Float16*)d_ws;

    hipLaunchKernelGGL(prep_kernel, dim3(512), dim3(256), 0, stream,
                       W_ih1, W_hh1, b_ih1, b_hh1, W_ih2, W_hh2, b_ih2, b_hh2, Wl, wsA);
    hipLaunchKernelGGL(lstm_kernel, dim3(NBLK), dim3(NTHR), 0, stream,
                       input, wsA, bl, T, steps, (float*)d_out);
}

// Round 9
// 398.047 us; speedup vs baseline: 1.2857x; 1.1880x over previous
//
#include <hip/hip_runtime.h>
#include <hip/hip_bf16.h>

#define HID 101
#define BATCH 1024
#define RPB 4
#define NBLK 256
#define NTHR 512
#define TSEQ 256

#define A1SZ  (7*4*4*512)    // 57344 halfs
#define A2SZ  (7*4*7*512)    // 100352 halfs
#define A2OFF A1SZ
#define AOOFF (A1SZ + A2SZ)  // 157696
#define AOSZ  (4*512)

typedef _Float16 h8 __attribute__((ext_vector_type(8)));
typedef float f4 __attribute__((ext_vector_type(4)));

// ---------------------------------------------------------------------------
// Combined state vector (K=224, 7 k-tiles of 32):
//   k 0..100 : h1    k 101..103 : x    k 104 : one    k 112..212 : h2
// A1 (L1, kt0..3): k<101->W_hh1[g][k]; 101..103->W_ih1; 104->b1; else 0.
// A2 (L2, kt0..6): k<101->W_ih2[g][k]; 104->b2; 112..212->W_hh2[g][k-112]; else 0.
// AO (out head, frags for kt3..6): row j<3: k 112..212 -> Wl[j][k-112]; else 0.
// Fragment: lane l holds A[row=l&15][k = kt*32 + ((l>>4)&3)*8 + i], i=0..7.
// ---------------------------------------------------------------------------
__global__ void prep_kernel(const float* __restrict__ W_ih1, const float* __restrict__ W_hh1,
                            const float* __restrict__ b_ih1, const float* __restrict__ b_hh1,
                            const float* __restrict__ W_ih2, const float* __restrict__ W_hh2,
                            const float* __restrict__ b_ih2, const float* __restrict__ b_hh2,
                            const float* __restrict__ Wl, _Float16* __restrict__ wsA) {
    int idx = blockIdx.x * blockDim.x + threadIdx.x;
    int stride = gridDim.x * blockDim.x;
    for (int t = idx; t < A1SZ; t += stride) {
        int i = t & 7, lane = (t >> 3) & 63, kt = (t >> 9) & 3, tau = (t >> 11) & 3, w = t >> 13;
        int k = kt * 32 + ((lane >> 4) & 3) * 8 + i;
        int u = 16 * w + (lane & 15);
        float v = 0.f;
        if (u < HID) {
            int g = tau * HID + u;
            if (k < HID) v = W_hh1[g * HID + k];
            else if (k >= 101 && k <= 103) v = W_ih1[g * 3 + (k - 101)];
            else if (k == 104) v = b_ih1[g] + b_hh1[g];
        }
        wsA[t] = (_Float16)v;
    }
    for (int t = idx; t < A2SZ; t += stride) {
        int i = t & 7, lane = (t >> 3) & 63;
        int rem = t >> 9;
        int kt = rem % 7; rem /= 7;
        int tau = rem & 3, w = rem >> 2;
        int k = kt * 32 + ((lane >> 4) & 3) * 8 + i;
        int u = 16 * w + (lane & 15);
        float v = 0.f;
        if (u < HID) {
            int g = tau * HID + u;
            if (k < HID) v = W_ih2[g * HID + k];
            else if (k == 104) v = b_ih2[g] + b_hh2[g];
            else if (k >= 112 && k < 213) v = W_hh2[g * HID + (k - 112)];
        }
        wsA[A2OFF + t] = (_Float16)v;
    }
    for (int t = idx; t < AOSZ; t += stride) {
        int i = t & 7, lane = (t >> 3) & 63, kk = (t >> 9) & 3;
        int k = (kk + 3) * 32 + ((lane >> 4) & 3) * 8 + i;
        int j = lane & 15;
        float v = (j < 3 && k >= 112 && k < 213) ? Wl[j * HID + (k - 112)] : 0.f;
        wsA[AOOFF + t] = (_Float16)v;
    }
}

__device__ __forceinline__ float sigm(float z) {
    return __builtin_amdgcn_rcpf(1.f + __expf(-z));
}
__device__ __forceinline__ float tanhf_(float z) {
    return 1.f - 2.f * __builtin_amdgcn_rcpf(__expf(2.f * z) + 1.f);
}

#define MFMA(acc, a, b) acc = __builtin_amdgcn_mfma_f32_16x16x32_f16(a, b, acc, 0, 0, 0)

// ---------------------------------------------------------------------------
// persistent kernel: 256 blocks x 512 thr (8 waves).
// Teacher-forced pipeline, ONE barrier per timestep:
//   stage(t): A(t) [needs h1(t-1),x(t)] || B(t-1) [needs h1(t-1),h2(t-2)]
//             || wave7: out(t-2) + stage x(t+1).
//   All reads from S[t&1]; all writes to S[1-(t&1)].
// Future steps: serial 3-barrier shape (feedback dependency).
// ---------------------------------------------------------------------------
__global__ __launch_bounds__(NTHR, 2) void lstm_kernel(
    const float* __restrict__ input, const _Float16* __restrict__ wsA,
    const float* __restrict__ bl, int steps, float* __restrict__ out)
{
    const int tid = threadIdx.x;
    const int wid = tid >> 6, lane = tid & 63;
    const int q = lane >> 4, col = lane & 15;
    const int r0 = blockIdx.x * RPB;
    const int ostride = steps * 3;

    __shared__ _Float16 Sb[2][3584];       // combined state buffers
    __shared__ float zwA[7][4][4][16];     // L1 z exchange
    __shared__ float zwB[7][4][4][16];     // L2 z exchange
    __shared__ _Float16 xpre[TSEQ * 12];   // staged inputs (f16)

    // --- weights: volatile loads -> execute once, stay register-resident ---
    h8 A1[4][4];
    h8 A2[4][7];
    if (wid < 7) {
        #pragma unroll
        for (int tau = 0; tau < 4; tau++) {
            #pragma unroll
            for (int kt = 0; kt < 4; kt++)
                A1[tau][kt] = *(const volatile h8*)(
                    wsA + ((size_t)((wid * 4 + tau) * 4 + kt) * 512 + lane * 8));
            #pragma unroll
            for (int kt = 0; kt < 7; kt++)
                A2[tau][kt] = *(const volatile h8*)(
                    wsA + (size_t)A2OFF + ((size_t)((wid * 4 + tau) * 7 + kt) * 512 + lane * 8));
        }
    } else {
        #pragma unroll
        for (int kt = 0; kt < 4; kt++)
            A2[0][kt] = *(const volatile h8*)(
                wsA + (size_t)AOOFF + ((size_t)(kt) * 512 + lane * 8));
    }
    const float bl0 = bl[0], bl1 = bl[1], bl2 = bl[2];

    // loop-invariant lane geometry
    const int r_ew = lane & 3, ul = lane >> 2;
    const int u = 16 * wid + ul;
    const bool ewv = (wid < 7) && (u < HID);
    const int hs1 = (u >> 3) * 128 + r_ew * 8 + (u & 7);            // h1 slot (k=u)
    const int hs2 = (14 + (u >> 3)) * 128 + r_ew * 8 + (u & 7);     // h2 slot (k=112+u)
    const int boff = q * 128 + col * 8;
    const int xr = lane / 3, xj = lane - 3 * xr;                    // wave7 lanes<12
    const int xoff = 12 * 128 + xr * 8 + 5 + xj;                    // x slot (k=101+xj)

    // ---- prologue ----
    for (int i2 = tid; i2 < 3584; i2 += NTHR) {
        Sb[0][i2] = (_Float16)0.f; Sb[1][i2] = (_Float16)0.f;
    }
    for (int g = tid; g < RPB * TSEQ * 3; g += NTHR) {
        int r = g / (TSEQ * 3), rem = g - r * (TSEQ * 3);
        int tt = rem / 3, j = rem - 3 * tt;
        xpre[tt * 12 + r * 3 + j] = (_Float16)input[(size_t)(r0 + r) * (TSEQ * 3) + rem];
    }
    __syncthreads();
    if (tid < 16) {   // bias-one slot k=104, both buffers
        Sb[0][13 * 128 + tid * 8] = (_Float16)1.0f;
        Sb[1][13 * 128 + tid * 8] = (_Float16)1.0f;
    }
    if (tid < 12) {   // x(0) -> S[0]
        int r = tid / 3, j = tid - 3 * (tid / 3);
        Sb[0][12 * 128 + r * 8 + 5 + j] = xpre[r * 3 + j];
    }
    float c1 = 0.f, c2 = 0.f;
    __syncthreads();

    // ---- teacher-forced pipeline: 1 barrier per step ----
    for (int t = 0; t < TSEQ; ++t) {
        _Float16* Rb = Sb[t & 1];
        _Float16* Wt = Sb[1 - (t & 1)];
        if (wid < 7) {
            // shared B-fragments (kt0..6) of S[p]
            h8 bf0 = (_Float16)0.f, bf1 = bf0, bf2 = bf0, bf3 = bf0,
               bf4 = bf0, bf5 = bf0, bf6 = bf0;
            if (col < 4) {
                bf0 = *(const h8*)(Rb + 0 * 512 + boff);
                bf1 = *(const h8*)(Rb + 1 * 512 + boff);
                bf2 = *(const h8*)(Rb + 2 * 512 + boff);
                bf3 = *(const h8*)(Rb + 3 * 512 + boff);
                bf4 = *(const h8*)(Rb + 4 * 512 + boff);
                bf5 = *(const h8*)(Rb + 5 * 512 + boff);
                bf6 = *(const h8*)(Rb + 6 * 512 + boff);
            }
            // ---- A(t): L1 over kt0..3 ----
            f4 a0 = {0.f,0.f,0.f,0.f}, a1 = a0, a2 = a0, a3 = a0;
            MFMA(a0, A1[0][0], bf0); MFMA(a1, A1[1][0], bf0); MFMA(a2, A1[2][0], bf0); MFMA(a3, A1[3][0], bf0);
            MFMA(a0, A1[0][1], bf1); MFMA(a1, A1[1][1], bf1); MFMA(a2, A1[2][1], bf1); MFMA(a3, A1[3][1], bf1);
            MFMA(a0, A1[0][2], bf2); MFMA(a1, A1[1][2], bf2); MFMA(a2, A1[2][2], bf2); MFMA(a3, A1[3][2], bf2);
            MFMA(a0, A1[0][3], bf3); MFMA(a1, A1[1][3], bf3); MFMA(a2, A1[2][3], bf3); MFMA(a3, A1[3][3], bf3);
            if (col < 4) {
                *(f4*)&zwA[wid][0][col][4 * q] = a0;
                *(f4*)&zwA[wid][1][col][4 * q] = a1;
                *(f4*)&zwA[wid][2][col][4 * q] = a2;
                *(f4*)&zwA[wid][3][col][4 * q] = a3;
            }
            // ---- B(t-1): L2 over kt0..6 ----
            if (t >= 1) {
                f4 b0 = {0.f,0.f,0.f,0.f}, b1 = b0, b2 = b0, b3 = b0;
                MFMA(b0, A2[0][0], bf0); MFMA(b1, A2[1][0], bf0); MFMA(b2, A2[2][0], bf0); MFMA(b3, A2[3][0], bf0);
                MFMA(b0, A2[0][1], bf1); MFMA(b1, A2[1][1], bf1); MFMA(b2, A2[2][1], bf1); MFMA(b3, A2[3][1], bf1);
                MFMA(b0, A2[0][2], bf2); MFMA(b1, A2[1][2], bf2); MFMA(b2, A2[2][2], bf2); MFMA(b3, A2[3][2], bf2);
                MFMA(b0, A2[0][3], bf3); MFMA(b1, A2[1][3], bf3); MFMA(b2, A2[2][3], bf3); MFMA(b3, A2[3][3], bf3);
                MFMA(b0, A2[0][4], bf4); MFMA(b1, A2[1][4], bf4); MFMA(b2, A2[2][4], bf4); MFMA(b3, A2[3][4], bf4);
                MFMA(b0, A2[0][5], bf5); MFMA(b1, A2[1][5], bf5); MFMA(b2, A2[2][5], bf5); MFMA(b3, A2[3][5], bf5);
                MFMA(b0, A2[0][6], bf6); MFMA(b1, A2[1][6], bf6); MFMA(b2, A2[2][6], bf6); MFMA(b3, A2[3][6], bf6);
                if (col < 4) {
                    *(f4*)&zwB[wid][0][col][4 * q] = b0;
                    *(f4*)&zwB[wid][1][col][4 * q] = b1;
                    *(f4*)&zwB[wid][2][col][4 * q] = b2;
                    *(f4*)&zwB[wid][3][col][4 * q] = b3;
                }
            }
            // ---- ew A -> h1(t) -> Wt ----
            {
                float z0 = zwA[wid][0][r_ew][ul], z1 = zwA[wid][1][r_ew][ul];
                float z2 = zwA[wid][2][r_ew][ul], z3 = zwA[wid][3][r_ew][ul];
                float ig = sigm(z0), fg = sigm(z1), gg = tanhf_(z2), og = sigm(z3);
                c1 = fg * c1 + ig * gg;
                float h1v = og * tanhf_(c1);
                if (ewv) Wt[hs1] = (_Float16)h1v;
            }
            // ---- ew B -> h2(t-1) -> Wt ----
            if (t >= 1) {
                float z0 = zwB[wid][0][r_ew][ul], z1 = zwB[wid][1][r_ew][ul];
                float z2 = zwB[wid][2][r_ew][ul], z3 = zwB[wid][3][r_ew][ul];
                float ig = sigm(z0), fg = sigm(z1), gg = tanhf_(z2), og = sigm(z3);
                c2 = fg * c2 + ig * gg;
                float h2v = og * tanhf_(c2);
                if (ewv) Wt[hs2] = (_Float16)h2v;
            }
        } else {
            // ---- wave 7: out(t-2) from Rb h2-region; stage x(t+1) -> Wt ----
            if (t >= 2) {
                f4 ao = {0.f, 0.f, 0.f, 0.f};
                #pragma unroll
                for (int kk = 0; kk < 4; kk++) {
                    h8 b = (_Float16)0.f;
                    if (col < 4) b = *(const h8*)(Rb + (kk + 3) * 512 + boff);
                    MFMA(ao, A2[0][kk], b);
                }
                if (lane < 4) {
                    float* op = out + (size_t)(r0 + lane) * ostride + (size_t)(t - 2) * 3;
                    op[0] = ao[0] + bl0; op[1] = ao[1] + bl1; op[2] = ao[2] + bl2;
                }
            }
            if (t + 1 < TSEQ && lane < 12)
                Wt[xoff] = xpre[(t + 1) * 12 + xr * 3 + xj];
        }
        __syncthreads();
    }

    // ---- drain stage (t=TSEQ): B(T-1) + out(T-2). reads S[0], h2(T-1)->S[1] ----
    {
        _Float16* Rb = Sb[0];
        _Float16* Wt = Sb[1];
        if (wid < 7) {
            h8 bf0 = (_Float16)0.f, bf1 = bf0, bf2 = bf0, bf3 = bf0,
               bf4 = bf0, bf5 = bf0, bf6 = bf0;
            if (col < 4) {
                bf0 = *(const h8*)(Rb + 0 * 512 + boff);
                bf1 = *(const h8*)(Rb + 1 * 512 + boff);
                bf2 = *(const h8*)(Rb + 2 * 512 + boff);
                bf3 = *(const h8*)(Rb + 3 * 512 + boff);
                bf4 = *(const h8*)(Rb + 4 * 512 + boff);
                bf5 = *(const h8*)(Rb + 5 * 512 + boff);
                bf6 = *(const h8*)(Rb + 6 * 512 + boff);
            }
            f4 b0 = {0.f,0.f,0.f,0.f}, b1 = b0, b2 = b0, b3 = b0;
            MFMA(b0, A2[0][0], bf0); MFMA(b1, A2[1][0], bf0); MFMA(b2, A2[2][0], bf0); MFMA(b3, A2[3][0], bf0);
            MFMA(b0, A2[0][1], bf1); MFMA(b1, A2[1][1], bf1); MFMA(b2, A2[2][1], bf1); MFMA(b3, A2[3][1], bf1);
            MFMA(b0, A2[0][2], bf2); MFMA(b1, A2[1][2], bf2); MFMA(b2, A2[2][2], bf2); MFMA(b3, A2[3][2], bf2);
            MFMA(b0, A2[0][3], bf3); MFMA(b1, A2[1][3], bf3); MFMA(b2, A2[2][3], bf3); MFMA(b3, A2[3][3], bf3);
            MFMA(b0, A2[0][4], bf4); MFMA(b1, A2[1][4], bf4); MFMA(b2, A2[2][4], bf4); MFMA(b3, A2[3][4], bf4);
            MFMA(b0, A2[0][5], bf5); MFMA(b1, A2[1][5], bf5); MFMA(b2, A2[2][5], bf5); MFMA(b3, A2[3][5], bf5);
            MFMA(b0, A2[0][6], bf6); MFMA(b1, A2[1][6], bf6); MFMA(b2, A2[2][6], bf6); MFMA(b3, A2[3][6], bf6);
            if (col < 4) {
                *(f4*)&zwB[wid][0][col][4 * q] = b0;
                *(f4*)&zwB[wid][1][col][4 * q] = b1;
                *(f4*)&zwB[wid][2][col][4 * q] = b2;
                *(f4*)&zwB[wid][3][col][4 * q] = b3;
            }
            float z0 = zwB[wid][0][r_ew][ul], z1 = zwB[wid][1][r_ew][ul];
            float z2 = zwB[wid][2][r_ew][ul], z3 = zwB[wid][3][r_ew][ul];
            float ig = sigm(z0), fg = sigm(z1), gg = tanhf_(z2), og = sigm(z3);
            c2 = fg * c2 + ig * gg;
            float h2v = og * tanhf_(c2);
            if (ewv) Wt[hs2] = (_Float16)h2v;
        } else {
            f4 ao = {0.f, 0.f, 0.f, 0.f};
            #pragma unroll
            for (int kk = 0; kk < 4; kk++) {
                h8 b = (_Float16)0.f;
                if (col < 4) b = *(const h8*)(Rb + (kk + 3) * 512 + boff);
                MFMA(ao, A2[0][kk], b);
            }
            if (lane < 4) {
                float* op = out + (size_t)(r0 + lane) * ostride + (size_t)(TSEQ - 2) * 3;
                op[0] = ao[0] + bl0; op[1] = ao[1] + bl1; op[2] = ao[2] + bl2;
            }
        }
        __syncthreads();
    }

    // ---- future (autoregressive), serial 3-barrier steps ----
    for (int t = TSEQ; t < steps; ++t) {
        _Float16* R = Sb[t & 1];
        _Float16* W = Sb[1 - (t & 1)];
        // pre: wave7 out(t-1) from W h2-region; feedback x(t) -> R x-slots
        if (wid == 7) {
            f4 ao = {0.f, 0.f, 0.f, 0.f};
            #pragma unroll
            for (int kk = 0; kk < 4; kk++) {
                h8 b = (_Float16)0.f;
                if (col < 4) b = *(const h8*)(W + (kk + 3) * 512 + boff);
                MFMA(ao, A2[0][kk], b);
            }
            if (lane < 4) {
                float o0 = ao[0] + bl0, o1 = ao[1] + bl1, o2 = ao[2] + bl2;
                float* op = out + (size_t)(r0 + lane) * ostride + (size_t)(t - 1) * 3;
                op[0] = o0; op[1] = o1; op[2] = o2;
                R[12 * 128 + lane * 8 + 5] = (_Float16)o0;
                R[12 * 128 + lane * 8 + 6] = (_Float16)o1;
                R[12 * 128 + lane * 8 + 7] = (_Float16)o2;
            }
        }
        __syncthreads();
        // A(t): read R kt0..3 -> h1(t) -> W h1-region
        if (wid < 7) {
            f4 a0 = {0.f,0.f,0.f,0.f}, a1 = a0, a2 = a0, a3 = a0;
            #pragma unroll
            for (int kt = 0; kt < 4; kt++) {
                h8 b = (_Float16)0.f;
                if (col < 4) b = *(const h8*)(R + kt * 512 + boff);
                MFMA(a0, A1[0][kt], b); MFMA(a1, A1[1][kt], b);
                MFMA(a2, A1[2][kt], b); MFMA(a3, A1[3][kt], b);
            }
            if (col < 4) {
                *(f4*)&zwA[wid][0][col][4 * q] = a0;
                *(f4*)&zwA[wid][1][col][4 * q] = a1;
                *(f4*)&zwA[wid][2][col][4 * q] = a2;
                *(f4*)&zwA[wid][3][col][4 * q] = a3;
            }
            float z0 = zwA[wid][0][r_ew][ul], z1 = zwA[wid][1][r_ew][ul];
            float z2 = zwA[wid][2][r_ew][ul], z3 = zwA[wid][3][r_ew][ul];
            float ig = sigm(z0), fg = sigm(z1), gg = tanhf_(z2), og = sigm(z3);
            c1 = fg * c1 + ig * gg;
            float h1v = og * tanhf_(c1);
            if (ewv) W[hs1] = (_Float16)h1v;
        }
        __syncthreads();
        // B(t): read W kt0..6 (h1(t), h2(t-1)) -> h2(t) -> R h2-region
        if (wid < 7) {
            f4 b0 = {0.f,0.f,0.f,0.f}, b1 = b0, b2 = b0, b3 = b0;
            #pragma unroll
            for (int kt = 0; kt < 7; kt++) {
                h8 b = (_Float16)0.f;
                if (col < 4) b = *(const h8*)(W + kt * 512 + boff);
                MFMA(b0, A2[0][kt], b); MFMA(b1, A2[1][kt], b);
                MFMA(b2, A2[2][kt], b); MFMA(b3, A2[3][kt], b);
            }
            if (col < 4) {
                *(f4*)&zwB[wid][0][col][4 * q] = b0;
                *(f4*)&zwB[wid][1][col][4 * q] = b1;
                *(f4*)&zwB[wid][2][col][4 * q] = b2;
                *(f4*)&zwB[wid][3][col][4 * q] = b3;
            }
            float z0 = zwB[wid][0][r_ew][ul], z1 = zwB[wid][1][r_ew][ul];
            float z2 = zwB[wid][2][r_ew][ul], z3 = zwB[wid][3][r_ew][ul];
            float ig = sigm(z0), fg = sigm(z1), gg = tanhf_(z2), og = sigm(z3);
            c2 = fg * c2 + ig * gg;
            float h2v = og * tanhf_(c2);
            if (ewv) R[hs2] = (_Float16)h2v;
        }
        __syncthreads();
    }

    // ---- epilogue: out(steps-1) from h2(steps-1) in Sb[1] ----
    if (wid == 7) {
        f4 ao = {0.f, 0.f, 0.f, 0.f};
        #pragma unroll
        for (int kk = 0; kk < 4; kk++) {
            h8 b = (_Float16)0.f;
            if (col < 4) b = *(const h8*)(&Sb[1][0] + (kk + 3) * 512 + boff);
            MFMA(ao, A2[0][kk], b);
        }
        if (lane < 4) {
            float* op = out + (size_t)(r0 + lane) * ostride + (size_t)(steps - 1) * 3;
            op[0] = ao[0] + bl0; op[1] = ao[1] + bl1; op[2] = ao[2] + bl2;
        }
    }
}

extern "C" void kernel_launch(void* const* d_in, const int* in_sizes, int n_in,
                              void* d_out, int out_size, void* d_ws, size_t ws_size,
                              hipStream_t stream) {
    const float* input = (const float*)d_in[0];
    const float* W_ih1 = (const float*)d_in[1];
    const float* W_hh1 = (const float*)d_in[2];
    const float* b_ih1 = (const float*)d_in[3];
    const float* b_hh1 = (const float*)d_in[4];
    const float* W_ih2 = (const float*)d_in[5];
    const float* W_hh2 = (const float*)d_in[6];
    const float* b_ih2 = (const float*)d_in[7];
    const float* b_hh2 = (const float*)d_in[8];
    const float* Wl    = (const float*)d_in[9];
    const float* bl    = (const float*)d_in[10];
    int steps = out_size / (BATCH * 3);       // 288
    _Float16* wsA = (_Float16*)d_ws;

    hipLaunchKernelGGL(prep_kernel, dim3(512), dim3(256), 0, stream,
                       W_ih1, W_hh1, b_ih1, b_hh1, W_ih2, W_hh2, b_ih2, b_hh2, Wl, wsA);
    hipLaunchKernelGGL(lstm_kernel, dim3(NBLK), dim3(NTHR), 0, stream,
                       input, wsA, bl, steps, (float*)d_out);
}